// Round 4
// baseline (256.425 us; speedup 1.0000x reference)
//
#include <hip/hip_runtime.h>

// SSIM (window=8 box sums) over 96 images of 512x512 fp32.
// v4: wave-autonomous, zero barriers, zero spills.
//  - one 64-lane wave per (image, 16-row strip); lane owns 8 columns
//  - vertical sliding window: register ring of raw pixels (8 rows x 8 cols x 2
//    images = 128 VGPRs, literal-indexed via 8x unrolled macro)
//  - horizontal 8-sum: intra-wave LDS exchange (single-wave workgroup => no
//    s_barrier; wave_barrier+sched_barrier(0) pin ds_write -> ds_read order;
//    DS pipe is in-order per wave)
//  - 2-deep global prefetch (double-buffered regs, consume-then-issue) so the
//    vmcnt wait at consume covers ~2 row-times; no vmcnt(0) drain anywhere
//  - __launch_bounds__(64,2): VGPR cap 256 (v3 lesson: (128,4) caused 33 MB of
//    scratch spill traffic)

#define W 512
#define H 512
#define OW 505
#define OH 505
#define TH 16
#define NSTRIP ((OH + TH - 1) / TH)   // 32
#define NIMG 96
#define NPIX (96.0 * 505.0 * 505.0)   // 24482400

__device__ __forceinline__ float4 ld4(const float* p) { return *(const float4*)p; }
__device__ __forceinline__ float4 f4add(float4 a, float4 b) {
    return make_float4(a.x + b.x, a.y + b.y, a.z + b.z, a.w + b.w);
}
__device__ __forceinline__ float4 f4sub(float4 a, float4 b) {
    return make_float4(a.x - b.x, a.y - b.y, a.z - b.z, a.w - b.w);
}
__device__ __forceinline__ float4 f4mul(float4 a, float4 b) {
    return make_float4(a.x * b.x, a.y * b.y, a.z * b.z, a.w * b.w);
}

__global__ void finalize(const double* p, float* out) {
    out[0] = 1.0f - (float)(*p / NPIX);
}

__global__ void __launch_bounds__(64, 2)
ssim_main(const float* __restrict__ gt, const float* __restrict__ ni,
          double* __restrict__ acc_out)
{
    const int lane = threadIdx.x;               // 0..63
    const int img  = blockIdx.y;
    const int R0   = blockIdx.x * TH;           // first output row (mult of 8)
    const int R1   = min(R0 + TH, OH);
    const int c0   = lane * 8;                  // lane owns cols c0..c0+7

    const float C1 = 1e-4f, C2 = 9e-4f;

    const float* gx = gt + (size_t)img * (W * H) + c0;
    const float* gy = ni + (size_t)img * (W * H) + c0;

    // per-wave horizontal-exchange buffer: [quantity][column]; width 520 so
    // lane 63 can read cols 512..519 (garbage, predicated out).
    __shared__ float vbuf[4][520];

    // register ring of raw pixels (literal-indexed only)
    float4 rx[8][2], ry[8][2];

    float4 vsx0 = make_float4(0,0,0,0), vsx1 = make_float4(0,0,0,0);  // sum x
    float4 vsy0 = make_float4(0,0,0,0), vsy1 = make_float4(0,0,0,0);  // sum y
    float4 vsq0 = make_float4(0,0,0,0), vsq1 = make_float4(0,0,0,0);  // sum x^2+y^2
    float4 vsp0 = make_float4(0,0,0,0), vsp1 = make_float4(0,0,0,0);  // sum x*y

    // warm-up: rows R0..R0+6 -> ring slots 0..6; slot 7 = zeros
#pragma unroll
    for (int k = 0; k < 7; ++k) {
        const float* bx = gx + (size_t)(R0 + k) * W;
        const float* by = gy + (size_t)(R0 + k) * W;
        float4 x0 = ld4(bx), x1 = ld4(bx + 4);
        float4 y0 = ld4(by), y1 = ld4(by + 4);
        rx[k][0] = x0; rx[k][1] = x1; ry[k][0] = y0; ry[k][1] = y1;
        vsx0 = f4add(vsx0, x0); vsx1 = f4add(vsx1, x1);
        vsy0 = f4add(vsy0, y0); vsy1 = f4add(vsy1, y1);
        vsq0 = f4add(vsq0, f4add(f4mul(x0,x0), f4mul(y0,y0)));
        vsq1 = f4add(vsq1, f4add(f4mul(x1,x1), f4mul(y1,y1)));
        vsp0 = f4add(vsp0, f4mul(x0,y0));
        vsp1 = f4add(vsp1, f4mul(x1,y1));
    }
    rx[7][0] = rx[7][1] = ry[7][0] = ry[7][1] = make_float4(0,0,0,0);

    // 2-deep prefetch: buf0 <- row R0+7, buf1 <- row R0+8 (R0+8 <= 504 always)
    float4 pfx[2][2], pfy[2][2];
    {
        const float* bx = gx + (size_t)(R0 + 7) * W;
        const float* by = gy + (size_t)(R0 + 7) * W;
        pfx[0][0] = ld4(bx); pfx[0][1] = ld4(bx + 4);
        pfy[0][0] = ld4(by); pfy[0][1] = ld4(by + 4);
    }
    {
        const float* bx = gx + (size_t)(R0 + 8) * W;
        const float* by = gy + (size_t)(R0 + 8) * W;
        pfx[1][0] = ld4(bx); pfx[1][1] = ld4(bx + 4);
        pfy[1][0] = ld4(by); pfy[1][1] = ld4(by + 4);
    }

    float acc = 0.0f;

#define HORIZ(S, v, n) {                                                  \
        float T = ((v[0]+v[1])+(v[2]+v[3])) + ((v[4]+v[5])+(v[6]+v[7]));  \
        S[0] = T;                                                         \
        _Pragma("unroll") for (int j = 1; j < 8; ++j)                     \
            S[j] = S[j-1] - v[j-1] + n[j-1];                              \
    }

#define ROWBODY(k, slot) {                                                \
        const int r = rbase + (k);                                        \
        if (r < R1) { /* wave-uniform */                                  \
            const int p = (k) & 1;                                        \
            float4 cx0 = pfx[p][0], cx1 = pfx[p][1];                      \
            float4 cy0 = pfy[p][0], cy1 = pfy[p][1];                      \
            if (r + 2 < R1) { /* issue row r+9, consumed at iter r+2 */   \
                const float* bx = gx + (size_t)(r + 9) * W;               \
                const float* by = gy + (size_t)(r + 9) * W;               \
                pfx[p][0] = ld4(bx); pfx[p][1] = ld4(bx + 4);             \
                pfy[p][0] = ld4(by); pfy[p][1] = ld4(by + 4);             \
            }                                                             \
            float4 ox0 = rx[slot][0], ox1 = rx[slot][1];                  \
            float4 oy0 = ry[slot][0], oy1 = ry[slot][1];                  \
            vsx0 = f4add(f4sub(vsx0, ox0), cx0);                          \
            vsx1 = f4add(f4sub(vsx1, ox1), cx1);                          \
            vsy0 = f4add(f4sub(vsy0, oy0), cy0);                          \
            vsy1 = f4add(f4sub(vsy1, oy1), cy1);                          \
            vsq0 = f4add(vsq0, f4sub(f4add(f4mul(cx0,cx0), f4mul(cy0,cy0)), \
                                     f4add(f4mul(ox0,ox0), f4mul(oy0,oy0)))); \
            vsq1 = f4add(vsq1, f4sub(f4add(f4mul(cx1,cx1), f4mul(cy1,cy1)), \
                                     f4add(f4mul(ox1,ox1), f4mul(oy1,oy1)))); \
            vsp0 = f4add(vsp0, f4sub(f4mul(cx0,cy0), f4mul(ox0,oy0)));    \
            vsp1 = f4add(vsp1, f4sub(f4mul(cx1,cy1), f4mul(ox1,oy1)));    \
            rx[slot][0] = cx0; rx[slot][1] = cx1;                         \
            ry[slot][0] = cy0; ry[slot][1] = cy1;                         \
            /* publish vertical sums (own 8 cols) */                      \
            *(float4*)&vbuf[0][c0] = vsx0; *(float4*)&vbuf[0][c0+4] = vsx1; \
            *(float4*)&vbuf[1][c0] = vsy0; *(float4*)&vbuf[1][c0+4] = vsy1; \
            *(float4*)&vbuf[2][c0] = vsq0; *(float4*)&vbuf[2][c0+4] = vsq1; \
            *(float4*)&vbuf[3][c0] = vsp0; *(float4*)&vbuf[3][c0+4] = vsp1; \
            __builtin_amdgcn_sched_barrier(0);                            \
            __builtin_amdgcn_wave_barrier();                              \
            __builtin_amdgcn_sched_barrier(0);                            \
            /* neighbor's 8 cols (c0+8..c0+15; need first 7) */           \
            float4 nx0 = *(float4*)&vbuf[0][c0+8], nx1 = *(float4*)&vbuf[0][c0+12]; \
            float4 ny0 = *(float4*)&vbuf[1][c0+8], ny1 = *(float4*)&vbuf[1][c0+12]; \
            float4 nq0 = *(float4*)&vbuf[2][c0+8], nq1 = *(float4*)&vbuf[2][c0+12]; \
            float4 np0 = *(float4*)&vbuf[3][c0+8], np1 = *(float4*)&vbuf[3][c0+12]; \
            float vx[8] = {vsx0.x,vsx0.y,vsx0.z,vsx0.w,vsx1.x,vsx1.y,vsx1.z,vsx1.w}; \
            float vy[8] = {vsy0.x,vsy0.y,vsy0.z,vsy0.w,vsy1.x,vsy1.y,vsy1.z,vsy1.w}; \
            float vq[8] = {vsq0.x,vsq0.y,vsq0.z,vsq0.w,vsq1.x,vsq1.y,vsq1.z,vsq1.w}; \
            float vp[8] = {vsp0.x,vsp0.y,vsp0.z,vsp0.w,vsp1.x,vsp1.y,vsp1.z,vsp1.w}; \
            float nx[8] = {nx0.x,nx0.y,nx0.z,nx0.w,nx1.x,nx1.y,nx1.z,nx1.w}; \
            float ny[8] = {ny0.x,ny0.y,ny0.z,ny0.w,ny1.x,ny1.y,ny1.z,ny1.w}; \
            float nq[8] = {nq0.x,nq0.y,nq0.z,nq0.w,nq1.x,nq1.y,nq1.z,nq1.w}; \
            float np[8] = {np0.x,np0.y,np0.z,np0.w,np1.x,np1.y,np1.z,np1.w}; \
            float Sx[8], Sy[8], Sq[8], Sp[8];                             \
            HORIZ(Sx, vx, nx) HORIZ(Sy, vy, ny)                           \
            HORIZ(Sq, vq, nq) HORIZ(Sp, vp, np)                           \
            _Pragma("unroll")                                             \
            for (int j = 0; j < 8; ++j) {                                 \
                float sx = Sx[j], sy = Sy[j];                             \
                float mu12 = sx * sy;                                     \
                float n1v = 2.0f * mu12 + C1;                             \
                float n2v = 2.0f * (Sp[j] - mu12) + C2;                   \
                float sx2 = sx * sx, sy2 = sy * sy;                       \
                float d1  = sx2 + sy2 + C1;                               \
                float d2  = (Sq[j] - sx2 - sy2) + C2;                     \
                float sv  = (n1v * n2v) * __builtin_amdgcn_rcpf(d1 * d2); \
                if (c0 + j < OW) acc += sv; /* only lane 63 partial */    \
            }                                                             \
        }                                                                 \
    }

    // rbase multiples of 8 from R0 (R0 mult of 8) -> ring slot (k+7)&7 literal
    for (int rbase = R0; rbase < R1; rbase += 8) {
        ROWBODY(0, 7)
        ROWBODY(1, 0)
        ROWBODY(2, 1)
        ROWBODY(3, 2)
        ROWBODY(4, 3)
        ROWBODY(5, 4)
        ROWBODY(6, 5)
        ROWBODY(7, 6)
    }

    // wave reduction -> one double atomic per wave
#pragma unroll
    for (int off = 32; off; off >>= 1) acc += __shfl_down(acc, off);
    if (lane == 0) atomicAdd(acc_out, (double)acc);
}

extern "C" void kernel_launch(void* const* d_in, const int* in_sizes, int n_in,
                              void* d_out, int out_size, void* d_ws, size_t ws_size,
                              hipStream_t stream) {
    const float* gt = (const float*)d_in[0];
    const float* ni = (const float*)d_in[1];
    double* acc = (double*)d_ws;   // 8 bytes scratch, re-poisoned every call

    hipMemsetAsync(acc, 0, sizeof(double), stream);
    dim3 grid(NSTRIP, NIMG);
    ssim_main<<<grid, 64, 0, stream>>>(gt, ni, acc);
    finalize<<<1, 1, 0, stream>>>(acc, (float*)d_out);
}

// Round 5
// 232.894 us; speedup vs baseline: 1.1010x; 1.1010x over previous
//
#include <hip/hip_runtime.h>

// SSIM (window=8 box sums) over 96 images of 512x512 fp32.
// v5 = v1/v3 structure with the round-3/4 pathologies removed:
//  - 128 threads x float4 = full 512-wide row; lane-stride 16 B LDS ops
//    (measured conflict-free in v1/v3; v4's 32 B stride hit 5.4M conflicts)
//  - register ring of raw pixels (16 float4 = 64 VGPRs), literal-indexed
//  - __launch_bounds__(128,2): VGPR cap 256. v3's (128,4) capped at 128 and
//    spilled 33 MB; v4's single-wave design spilled 47 MB. Footprint ~130.
//  - 4 quantities (x, y, x^2+y^2, x*y), double-buffered vbuf -> ONE
//    __syncthreads per row
//  - prefetch for row r+8 issued AFTER the barrier: at the barrier vmcnt is
//    already drained (consumed at loop top), so the drain is free, and the
//    load gets ~100 VALU ops of flight time before consumption
//  - TH=16 -> 3072 blocks (12 blocks/CU demand); LDS 16.7 KB caps at 9/CU

#define W 512
#define H 512
#define OW 505
#define OH 505
#define TH 16
#define NSTRIP ((OH + TH - 1) / TH)   // 32
#define NIMG 96
#define NPIX (96.0 * 505.0 * 505.0)   // 24482400

__device__ __forceinline__ float4 ld4(const float* p) { return *(const float4*)p; }
__device__ __forceinline__ float4 f4add(float4 a, float4 b) {
    return make_float4(a.x + b.x, a.y + b.y, a.z + b.z, a.w + b.w);
}
__device__ __forceinline__ float4 f4sub(float4 a, float4 b) {
    return make_float4(a.x - b.x, a.y - b.y, a.z - b.z, a.w - b.w);
}
__device__ __forceinline__ float4 f4mul(float4 a, float4 b) {
    return make_float4(a.x * b.x, a.y * b.y, a.z * b.z, a.w * b.w);
}

__global__ void finalize(const double* p, float* out) {
    out[0] = 1.0f - (float)(*p / NPIX);
}

__global__ void __launch_bounds__(128, 2)
ssim_main(const float* __restrict__ gt, const float* __restrict__ ni,
          double* __restrict__ acc_out)
{
    const int t   = threadIdx.x;      // 0..127
    const int c0  = t * 4;            // base column (0..508)
    const int img = blockIdx.y;
    const int R0  = blockIdx.x * TH;  // first output row of strip (mult of 8)
    const int R1  = min(R0 + TH, OH);

    const float C1 = 1e-4f;
    const float C2 = 9e-4f;

    const float* gx = gt + (size_t)img * (W * H) + c0;
    const float* gy = ni + (size_t)img * (W * H) + c0;

    // double-buffered vertical sums: [buf][quantity][column]; width 520 so
    // threads 126/127 can read past 512 (garbage, predicated out).
    __shared__ float vbuf[2][4][520];
    __shared__ float wpart[2];

    float4 ring_x[8], ring_y[8];
    float4 vsx = make_float4(0, 0, 0, 0);   // sum x
    float4 vsy = make_float4(0, 0, 0, 0);   // sum y
    float4 vsq = make_float4(0, 0, 0, 0);   // sum x^2 + y^2
    float4 vsp = make_float4(0, 0, 0, 0);   // sum x*y

    // warm-up: rows R0..R0+6 -> ring slots 0..6; slot 7 = zeros (no row leaves
    // the window at r == R0).
#pragma unroll
    for (int k = 0; k < 7; ++k) {
        float4 x = ld4(gx + (size_t)(R0 + k) * W);
        float4 y = ld4(gy + (size_t)(R0 + k) * W);
        ring_x[k] = x; ring_y[k] = y;
        vsx = f4add(vsx, x);
        vsy = f4add(vsy, y);
        vsq = f4add(vsq, f4add(f4mul(x, x), f4mul(y, y)));
        vsp = f4add(vsp, f4mul(x, y));
    }
    ring_x[7] = make_float4(0, 0, 0, 0);
    ring_y[7] = make_float4(0, 0, 0, 0);

    // prefetch first new row (R0+7 <= 511 always)
    float4 px = ld4(gx + (size_t)(R0 + 7) * W);
    float4 py = ld4(gy + (size_t)(R0 + 7) * W);

    float acc = 0.0f;

#define HORIZ(q, v) {                                                     \
        float4 n1 = *(float4*)&vbuf[b][q][c0 + 4];                        \
        float4 n2 = *(float4*)&vbuf[b][q][c0 + 8];                        \
        float s = ((v.x + v.y) + (v.z + v.w)) +                           \
                  ((n1.x + n1.y) + (n1.z + n1.w));                        \
        B[q][0] = s;                                                      \
        s += n2.x - v.x; B[q][1] = s;                                     \
        s += n2.y - v.y; B[q][2] = s;                                     \
        s += n2.z - v.z; B[q][3] = s;                                     \
    }

#define ROWBODY(k, slot) {                                                \
        const int r = rbase + (k);                                        \
        if (r < R1) { /* block-uniform */                                 \
            float4 cx = px, cy = py;   /* waits vmcnt here, not at barrier */ \
            float4 ox = ring_x[slot], oy = ring_y[slot];                  \
            vsx = f4add(f4sub(vsx, ox), cx);                              \
            vsy = f4add(f4sub(vsy, oy), cy);                              \
            vsq = f4add(vsq, f4sub(f4add(f4mul(cx, cx), f4mul(cy, cy)),   \
                                   f4add(f4mul(ox, ox), f4mul(oy, oy)))); \
            vsp = f4add(vsp, f4sub(f4mul(cx, cy), f4mul(ox, oy)));        \
            ring_x[slot] = cx; ring_y[slot] = cy;                         \
            const int b = r & 1;                                          \
            *(float4*)&vbuf[b][0][c0] = vsx;                              \
            *(float4*)&vbuf[b][1][c0] = vsy;                              \
            *(float4*)&vbuf[b][2][c0] = vsq;                              \
            *(float4*)&vbuf[b][3][c0] = vsp;                              \
            __syncthreads();                                              \
            if (r + 1 < R1) { /* issue row r+8 AFTER barrier (<512 ok) */ \
                px = ld4(gx + (size_t)(r + 8) * W);                       \
                py = ld4(gy + (size_t)(r + 8) * W);                       \
            }                                                             \
            float B[4][4];                                                \
            HORIZ(0, vsx); HORIZ(1, vsy); HORIZ(2, vsq); HORIZ(3, vsp);   \
            _Pragma("unroll")                                             \
            for (int j = 0; j < 4; ++j) {                                 \
                float Sx = B[0][j], Sy = B[1][j];                         \
                float Sq = B[2][j], Sp = B[3][j];                         \
                float mu12 = Sx * Sy;                                     \
                float n1v = 2.0f * mu12 + C1;                             \
                float n2v = 2.0f * (Sp - mu12) + C2;                      \
                float sx2 = Sx * Sx, sy2 = Sy * Sy;                       \
                float d1  = sx2 + sy2 + C1;                               \
                float d2  = (Sq - sx2 - sy2) + C2;                        \
                float sv  = (n1v * n2v) * __builtin_amdgcn_rcpf(d1 * d2); \
                if (c0 + j < OW) acc += sv;                               \
            }                                                             \
        }                                                                 \
    }

    // R0 and rbase are multiples of 8, so ring slot (r+7)&7 = (k+7)&7 (literal).
    for (int rbase = R0; rbase < R1; rbase += 8) {
        ROWBODY(0, 7)
        ROWBODY(1, 0)
        ROWBODY(2, 1)
        ROWBODY(3, 2)
        ROWBODY(4, 3)
        ROWBODY(5, 4)
        ROWBODY(6, 5)
        ROWBODY(7, 6)
    }

    // reduction: wave shuffle -> LDS -> one double atomic per block
#pragma unroll
    for (int off = 32; off > 0; off >>= 1) acc += __shfl_down(acc, off);
    const int wave = t >> 6, lane = t & 63;
    if (lane == 0) wpart[wave] = acc;
    __syncthreads();
    if (t == 0) atomicAdd(acc_out, (double)(wpart[0] + wpart[1]));
}

extern "C" void kernel_launch(void* const* d_in, const int* in_sizes, int n_in,
                              void* d_out, int out_size, void* d_ws, size_t ws_size,
                              hipStream_t stream) {
    const float* gt = (const float*)d_in[0];
    const float* ni = (const float*)d_in[1];
    double* acc = (double*)d_ws;   // 8 bytes scratch, re-poisoned every call

    hipMemsetAsync(acc, 0, sizeof(double), stream);
    dim3 grid(NSTRIP, NIMG);
    ssim_main<<<grid, 128, 0, stream>>>(gt, ni, acc);
    finalize<<<1, 1, 0, stream>>>(acc, (float*)d_out);
}

// Round 6
// 229.403 us; speedup vs baseline: 1.1178x; 1.0152x over previous
//
#include <hip/hip_runtime.h>

// SSIM (window=8 box sums) over 96 images of 512x512 fp32.
// v6 = v5 with RPI=4 row batching to fix the latency structure:
//  - phase A: consume 4 prefetched rows, 4 vertical updates, publish 4 LDS
//    row-slots; ONE barrier; phase B: issue next 8 loads (8 KB in flight,
//    ~1400 cyc of phase-B VALU flight before the next barrier drains vmcnt),
//    then 4 rows of HORIZ+SSIM; ONE barrier.  -> barriers/block halved,
//    loads-in-flight 4x, flight time ~4x vs v5.
//  - LDS 33.3 KB = 4 blocks/CU = measured v5 residency (no occupancy loss)
//  - all DS ops keep v5's 16 B lane-stride (measured conflict-free)
//  - __launch_bounds__(128,2): VGPR cap 256, footprint ~170 -> no spill

#define W 512
#define H 512
#define OW 505
#define OH 505
#define TH 16
#define NSTRIP ((OH + TH - 1) / TH)   // 32
#define NIMG 96
#define NPIX (96.0 * 505.0 * 505.0)   // 24482400

__device__ __forceinline__ float4 ld4(const float* p) { return *(const float4*)p; }
__device__ __forceinline__ float4 f4add(float4 a, float4 b) {
    return make_float4(a.x + b.x, a.y + b.y, a.z + b.z, a.w + b.w);
}
__device__ __forceinline__ float4 f4sub(float4 a, float4 b) {
    return make_float4(a.x - b.x, a.y - b.y, a.z - b.z, a.w - b.w);
}
__device__ __forceinline__ float4 f4mul(float4 a, float4 b) {
    return make_float4(a.x * b.x, a.y * b.y, a.z * b.z, a.w * b.w);
}

__global__ void finalize(const double* p, float* out) {
    out[0] = 1.0f - (float)(*p / NPIX);
}

__global__ void __launch_bounds__(128, 2)
ssim_main(const float* __restrict__ gt, const float* __restrict__ ni,
          double* __restrict__ acc_out)
{
    const int t   = threadIdx.x;      // 0..127
    const int c0  = t * 4;            // base column (0..508)
    const int img = blockIdx.y;
    const int R0  = blockIdx.x * TH;  // first output row of strip (mult of 8)
    const int R1  = min(R0 + TH, OH);

    const float C1 = 1e-4f;
    const float C2 = 9e-4f;

    const float* gx = gt + (size_t)img * (W * H) + c0;
    const float* gy = ni + (size_t)img * (W * H) + c0;

    // 4 row-slots x 4 quantities x 520 cols (width 520: threads 126/127 read
    // past col 511 -> garbage, predicated out of the accumulate).
    __shared__ float vbuf[4][4][520];
    __shared__ float wpart[2];

    float4 ring_x[8], ring_y[8];
    float4 vsx = make_float4(0, 0, 0, 0);   // sum x
    float4 vsy = make_float4(0, 0, 0, 0);   // sum y
    float4 vsq = make_float4(0, 0, 0, 0);   // sum x^2 + y^2
    float4 vsp = make_float4(0, 0, 0, 0);   // sum x*y

    // warm-up: rows R0..R0+6 -> ring slots 0..6; slot 7 = zeros
#pragma unroll
    for (int k = 0; k < 7; ++k) {
        float4 x = ld4(gx + (size_t)(R0 + k) * W);
        float4 y = ld4(gy + (size_t)(R0 + k) * W);
        ring_x[k] = x; ring_y[k] = y;
        vsx = f4add(vsx, x);
        vsy = f4add(vsy, y);
        vsq = f4add(vsq, f4add(f4mul(x, x), f4mul(y, y)));
        vsp = f4add(vsp, f4mul(x, y));
    }
    ring_x[7] = make_float4(0, 0, 0, 0);
    ring_y[7] = make_float4(0, 0, 0, 0);

    // prefetch rows R0+7..R0+10 (all <= 506 < 512; every strip has >= 9 rows)
    float4 pfx[4], pfy[4];
#pragma unroll
    for (int m = 0; m < 4; ++m) {
        pfx[m] = ld4(gx + (size_t)(R0 + 7 + m) * W);
        pfy[m] = ld4(gy + (size_t)(R0 + 7 + m) * W);
    }

    float acc = 0.0f;

// phase A, one row: consume prefetch slot m, slide vsums, publish LDS row m
#define PHASEA_ROW(rb, m, slot) {                                         \
        if ((rb) + (m) < R1) { /* block-uniform */                        \
            float4 cx = pfx[m], cy = pfy[m];                              \
            float4 ox = ring_x[slot], oy = ring_y[slot];                  \
            vsx = f4add(f4sub(vsx, ox), cx);                              \
            vsy = f4add(f4sub(vsy, oy), cy);                              \
            vsq = f4add(vsq, f4sub(f4add(f4mul(cx, cx), f4mul(cy, cy)),   \
                                   f4add(f4mul(ox, ox), f4mul(oy, oy)))); \
            vsp = f4add(vsp, f4sub(f4mul(cx, cy), f4mul(ox, oy)));        \
            ring_x[slot] = cx; ring_y[slot] = cy;                         \
            *(float4*)&vbuf[m][0][c0] = vsx;                              \
            *(float4*)&vbuf[m][1][c0] = vsy;                              \
            *(float4*)&vbuf[m][2][c0] = vsq;                              \
            *(float4*)&vbuf[m][3][c0] = vsp;                              \
        }                                                                 \
    }

// 8-wide horizontal sliding sums from 3 LDS float4s (own, +4, +8)
#define HORIZ(q) {                                                        \
        float4 o = *(float4*)&vbuf[m][q][c0];                             \
        float4 a = *(float4*)&vbuf[m][q][c0 + 4];                         \
        float4 e = *(float4*)&vbuf[m][q][c0 + 8];                         \
        float s = ((o.x + o.y) + (o.z + o.w)) +                           \
                  ((a.x + a.y) + (a.z + a.w));                            \
        B[q][0] = s;                                                      \
        s += e.x - o.x; B[q][1] = s;                                      \
        s += e.y - o.y; B[q][2] = s;                                      \
        s += e.z - o.z; B[q][3] = s;                                      \
    }

// phase B, one row: horizontal sums + SSIM + accumulate
#define PHASEB_ROW(rb, mm) {                                              \
        if ((rb) + (mm) < R1) { /* block-uniform */                       \
            const int m = (mm);                                           \
            float B[4][4];                                                \
            HORIZ(0) HORIZ(1) HORIZ(2) HORIZ(3)                           \
            _Pragma("unroll")                                             \
            for (int j = 0; j < 4; ++j) {                                 \
                float Sx = B[0][j], Sy = B[1][j];                         \
                float Sq = B[2][j], Sp = B[3][j];                         \
                float mu12 = Sx * Sy;                                     \
                float n1v = 2.0f * mu12 + C1;                             \
                float n2v = 2.0f * (Sp - mu12) + C2;                      \
                float sx2 = Sx * Sx, sy2 = Sy * Sy;                       \
                float d1  = sx2 + sy2 + C1;                               \
                float d2  = (Sq - sx2 - sy2) + C2;                        \
                float sv  = (n1v * n2v) * __builtin_amdgcn_rcpf(d1 * d2); \
                if (c0 + j < OW) acc += sv;                               \
            }                                                             \
        }                                                                 \
    }

// one group = 4 rows: phase A, barrier, prefetch-issue, phase B, barrier
#define GROUP(rb, s0, s1, s2, s3) {                                       \
        if ((rb) < R1) { /* block-uniform */                              \
            PHASEA_ROW(rb, 0, s0) PHASEA_ROW(rb, 1, s1)                   \
            PHASEA_ROW(rb, 2, s2) PHASEA_ROW(rb, 3, s3)                   \
            __syncthreads();                                              \
            _Pragma("unroll")                                             \
            for (int m = 0; m < 4; ++m) { /* rows (rb)+11+m <= 511 */     \
                if ((rb) + 4 + m < R1) {                                  \
                    pfx[m] = ld4(gx + (size_t)((rb) + 11 + m) * W);       \
                    pfy[m] = ld4(gy + (size_t)((rb) + 11 + m) * W);       \
                }                                                         \
            }                                                             \
            PHASEB_ROW(rb, 0) PHASEB_ROW(rb, 1)                           \
            PHASEB_ROW(rb, 2) PHASEB_ROW(rb, 3)                           \
            __syncthreads();                                              \
        }                                                                 \
    }

    // R0 mult of 8 -> groups at rb0 (slots 7,0,1,2) and rb0+4 (slots 3,4,5,6)
    for (int rb0 = R0; rb0 < R1; rb0 += 8) {
        GROUP(rb0,     7, 0, 1, 2)
        GROUP(rb0 + 4, 3, 4, 5, 6)
    }

    // reduction: wave shuffle -> LDS -> one double atomic per block
#pragma unroll
    for (int off = 32; off > 0; off >>= 1) acc += __shfl_down(acc, off);
    const int wave = t >> 6, lane = t & 63;
    if (lane == 0) wpart[wave] = acc;
    __syncthreads();
    if (t == 0) atomicAdd(acc_out, (double)(wpart[0] + wpart[1]));
}

extern "C" void kernel_launch(void* const* d_in, const int* in_sizes, int n_in,
                              void* d_out, int out_size, void* d_ws, size_t ws_size,
                              hipStream_t stream) {
    const float* gt = (const float*)d_in[0];
    const float* ni = (const float*)d_in[1];
    double* acc = (double*)d_ws;   // 8 bytes scratch, re-poisoned every call

    hipMemsetAsync(acc, 0, sizeof(double), stream);
    dim3 grid(NSTRIP, NIMG);
    ssim_main<<<grid, 128, 0, stream>>>(gt, ni, acc);
    finalize<<<1, 1, 0, stream>>>(acc, (float*)d_out);
}